// Round 1
// baseline (831.697 us; speedup 1.0000x reference)
//
#include <hip/hip_runtime.h>
#include <math.h>

#define EPSF 2.2e-10f
#define NV 30000
#define NB 512

// ---------------------------------------------------------------- digamma
__device__ __forceinline__ float digammaf(float xx) {
    float x = xx, r = 0.f;
    while (x < 6.f) { r -= 1.f / x; x += 1.f; }
    float f = 1.f / (x * x);
    float s = logf(x) - 0.5f / x
        - f * (0.0833333333f - f * (0.0083333333f - f * (0.0039682540f
        - f * (0.0041666667f - f * 0.0075757576f))));
    return r + s;
}

// ---------------------------------------------------------------- K1: layer0 main
// denom = phi0@theta0 ; ratio = x^T/denom ; R0 = ratio@theta0^T ; NDot0 = 100*colsum(phi0*R0)
// writes ratio (transposed, (B,V)) and R0 (into d_out region)
__global__ __launch_bounds__(256) void k1_layer0(
    const float* __restrict__ x,       // (B,V)
    const float* __restrict__ phi0,    // (V,128)
    const float* __restrict__ theta0,  // (128,B)
    float* __restrict__ ratio_t,       // (B,V)
    float* __restrict__ R0,            // (V,128)  (= d_out region)
    float* __restrict__ NDot0)         // (128)
{
    __shared__ __align__(16) float phi_s[32][129];
    __shared__ __align__(16) float thA[128][36];   // [k][j]
    __shared__ __align__(16) float thB[32][132];   // [j][k]
    __shared__ __align__(16) float rat_s[32][33];

    const int t = threadIdx.x;
    const int vbase = blockIdx.x * 32;
    const int v_l = t & 31;
    const int kq  = t >> 5;        // 0..7
    const int jb  = kq * 4;
    const int k16 = kq * 16;
    const int vg  = vbase + v_l;

    for (int idx = t; idx < 32 * 128; idx += 256) {
        int v = idx >> 7, k = idx & 127;
        int vv = vbase + v;
        phi_s[v][k] = (vv < NV) ? phi0[vv * 128 + k] : 0.f;
    }

    float r0acc[16];
#pragma unroll
    for (int i = 0; i < 16; ++i) r0acc[i] = 0.f;

    for (int c = 0; c < 16; ++c) {
        const int b0 = c * 32;
        __syncthreads();   // phi ready (1st iter); prev phase-b done before overwrite
        for (int idx = t; idx < 4096; idx += 256) {
            int k = idx >> 5, j = idx & 31;
            thA[k][j] = theta0[k * NB + b0 + j];
        }
        __syncthreads();
        for (int idx = t; idx < 4096; idx += 256) {
            int k = idx >> 5, j = idx & 31;
            thB[j][k] = thA[k][j];
        }
        // phase a: denom + ratio (reads phi_s, thA)
        float d0 = 0.f, d1 = 0.f, d2 = 0.f, d3 = 0.f;
#pragma unroll 4
        for (int k = 0; k < 128; ++k) {
            float pv = phi_s[v_l][k];
            float4 tj = *(const float4*)&thA[k][jb];
            d0 = fmaf(pv, tj.x, d0); d1 = fmaf(pv, tj.y, d1);
            d2 = fmaf(pv, tj.z, d2); d3 = fmaf(pv, tj.w, d3);
        }
        float r0 = 0.f, r1 = 0.f, r2 = 0.f, r3 = 0.f;
        if (vg < NV) {
            r0 = x[(b0 + jb + 0) * NV + vg] / fmaxf(d0, EPSF);
            r1 = x[(b0 + jb + 1) * NV + vg] / fmaxf(d1, EPSF);
            r2 = x[(b0 + jb + 2) * NV + vg] / fmaxf(d2, EPSF);
            r3 = x[(b0 + jb + 3) * NV + vg] / fmaxf(d3, EPSF);
            ratio_t[(b0 + jb + 0) * NV + vg] = r0;
            ratio_t[(b0 + jb + 1) * NV + vg] = r1;
            ratio_t[(b0 + jb + 2) * NV + vg] = r2;
            ratio_t[(b0 + jb + 3) * NV + vg] = r3;
        }
        rat_s[v_l][jb + 0] = r0;
        rat_s[v_l][jb + 1] = r1;
        rat_s[v_l][jb + 2] = r2;
        rat_s[v_l][jb + 3] = r3;
        __syncthreads();   // thB + rat_s ready
        // phase b: R0 += ratio @ theta^T
#pragma unroll 4
        for (int j = 0; j < 32; ++j) {
            float rv = rat_s[v_l][j];
            float4 b0v = *(const float4*)&thB[j][k16 + 0];
            float4 b1v = *(const float4*)&thB[j][k16 + 4];
            float4 b2v = *(const float4*)&thB[j][k16 + 8];
            float4 b3v = *(const float4*)&thB[j][k16 + 12];
            r0acc[0]  = fmaf(rv, b0v.x, r0acc[0]);
            r0acc[1]  = fmaf(rv, b0v.y, r0acc[1]);
            r0acc[2]  = fmaf(rv, b0v.z, r0acc[2]);
            r0acc[3]  = fmaf(rv, b0v.w, r0acc[3]);
            r0acc[4]  = fmaf(rv, b1v.x, r0acc[4]);
            r0acc[5]  = fmaf(rv, b1v.y, r0acc[5]);
            r0acc[6]  = fmaf(rv, b1v.z, r0acc[6]);
            r0acc[7]  = fmaf(rv, b1v.w, r0acc[7]);
            r0acc[8]  = fmaf(rv, b2v.x, r0acc[8]);
            r0acc[9]  = fmaf(rv, b2v.y, r0acc[9]);
            r0acc[10] = fmaf(rv, b2v.z, r0acc[10]);
            r0acc[11] = fmaf(rv, b2v.w, r0acc[11]);
            r0acc[12] = fmaf(rv, b3v.x, r0acc[12]);
            r0acc[13] = fmaf(rv, b3v.y, r0acc[13]);
            r0acc[14] = fmaf(rv, b3v.z, r0acc[14]);
            r0acc[15] = fmaf(rv, b3v.w, r0acc[15]);
        }
    }
    // NDot0 partials: reduce over the 32-lane v group
    float nd[16];
#pragma unroll
    for (int i = 0; i < 16; ++i) nd[i] = phi_s[v_l][k16 + i] * r0acc[i];
#pragma unroll
    for (int i = 0; i < 16; ++i) {
        float s = nd[i];
        s += __shfl_xor(s, 1);  s += __shfl_xor(s, 2);
        s += __shfl_xor(s, 4);  s += __shfl_xor(s, 8);
        s += __shfl_xor(s, 16);
        nd[i] = s;
    }
    if (v_l == 0) {
#pragma unroll
        for (int i = 0; i < 16; ++i) atomicAdd(&NDot0[k16 + i], 100.f * nd[i]);
    }
    // stage R0 via LDS (reuse thB) for coalesced writeout
    __syncthreads();
    float (*R0s)[132] = thB;
#pragma unroll
    for (int i = 0; i < 16; ++i) R0s[v_l][k16 + i] = r0acc[i];
    __syncthreads();
    for (int idx = t; idx < 4096; idx += 256) {
        int v = idx >> 7, k = idx & 127;
        int vv = vbase + v;
        if (vv < NV) R0[vv * 128 + k] = R0s[v][k];
    }
}

// ---------------------------------------------------------------- K2: C0 = phi0^T @ ratio
__global__ __launch_bounds__(256) void k2_c0(
    const float* __restrict__ phi0,     // (V,128)
    const float* __restrict__ ratio_t,  // (B,V)
    float* __restrict__ C0)             // (128,B), pre-zeroed, atomic
{
    __shared__ __align__(16) float phi_s[32][132];
    __shared__ __align__(16) float rat_s[32][36];
    const int t = threadIdx.x;
    const int b0 = blockIdx.x * 32;     // 16 tiles
    const int vs = blockIdx.y;          // 63 splits x 480 rows
    const int kq = t >> 3, bq = t & 7;
    const int k4 = kq * 4, b4 = bq * 4;
    float acc[16];
#pragma unroll
    for (int i = 0; i < 16; ++i) acc[i] = 0.f;

    for (int cc = 0; cc < 15; ++cc) {
        int vb = vs * 480 + cc * 32;
        __syncthreads();
        for (int idx = t; idx < 4096; idx += 256) {
            int v = idx >> 7, k = idx & 127;
            int vv = vb + v;
            phi_s[v][k] = (vv < NV) ? phi0[vv * 128 + k] : 0.f;
        }
        for (int idx = t; idx < 1024; idx += 256) {
            int b = idx >> 5, v = idx & 31;
            int vv = vb + v;
            rat_s[v][b] = (vv < NV) ? ratio_t[(b0 + b) * NV + vv] : 0.f;
        }
        __syncthreads();
#pragma unroll 4
        for (int v = 0; v < 32; ++v) {
            float4 a  = *(const float4*)&phi_s[v][k4];
            float4 bv = *(const float4*)&rat_s[v][b4];
            acc[0]  = fmaf(a.x, bv.x, acc[0]);  acc[1]  = fmaf(a.x, bv.y, acc[1]);
            acc[2]  = fmaf(a.x, bv.z, acc[2]);  acc[3]  = fmaf(a.x, bv.w, acc[3]);
            acc[4]  = fmaf(a.y, bv.x, acc[4]);  acc[5]  = fmaf(a.y, bv.y, acc[5]);
            acc[6]  = fmaf(a.y, bv.z, acc[6]);  acc[7]  = fmaf(a.y, bv.w, acc[7]);
            acc[8]  = fmaf(a.z, bv.x, acc[8]);  acc[9]  = fmaf(a.z, bv.y, acc[9]);
            acc[10] = fmaf(a.z, bv.z, acc[10]); acc[11] = fmaf(a.z, bv.w, acc[11]);
            acc[12] = fmaf(a.w, bv.x, acc[12]); acc[13] = fmaf(a.w, bv.y, acc[13]);
            acc[14] = fmaf(a.w, bv.z, acc[14]); acc[15] = fmaf(a.w, bv.w, acc[15]);
        }
    }
#pragma unroll
    for (int i = 0; i < 4; ++i)
#pragma unroll
        for (int j = 0; j < 4; ++j)
            atomicAdd(&C0[(k4 + i) * NB + b0 + b4 + j], acc[i * 4 + j]);
}

// ---------------------------------------------------------------- layer0 finalize
__global__ __launch_bounds__(256) void k3_step(
    const float* __restrict__ phi0, const float* __restrict__ noise0,
    const float* __restrict__ NDot0, float* __restrict__ out /* holds R0, -> step */,
    float* __restrict__ stepsum0)
{
    __shared__ float red[256];
    const int t = threadIdx.x;
    const int k = t & 127;
    const int base = blockIdx.x * 2048;
    float nd = NDot0[k];
    float inv_n = 1.f / fmaxf(nd, EPSF);
    float tmpsum = nd + 3000.f;           // NDot + 0.1*30000
    float ssum = 0.f;
#pragma unroll
    for (int i = 0; i < 8; ++i) {
        int e = base + i * 256 + t;
        float phi = phi0[e], R = out[e], nz = noise0[e];
        float tmp = fmaf(100.f * phi, R, 0.1f);
        float step = phi + inv_n * (tmp - tmpsum * phi) + sqrtf(2.f * inv_n * phi) * nz;
        out[e] = step;
        ssum += step;
    }
    red[t] = ssum;
    __syncthreads();
    if (t < 128) atomicAdd(&stepsum0[k], red[t] + red[t + 128]);
}

__global__ __launch_bounds__(256) void k4_proj(
    const float* __restrict__ phi0, const float* __restrict__ stepsum0,
    float* __restrict__ out, float* __restrict__ psum0)
{
    __shared__ float red[256];
    const int t = threadIdx.x;
    const int k = t & 127;
    const int base = blockIdx.x * 2048;
    const float ss = stepsum0[k] - 1.f;
    float ps = 0.f;
#pragma unroll
    for (int i = 0; i < 8; ++i) {
        int e = base + i * 256 + t;
        float p = out[e] - ss * phi0[e];
        p = fmaxf(EPSF, p);
        out[e] = p;
        ps += p;
    }
    red[t] = ps;
    __syncthreads();
    if (t < 128) atomicAdd(&psum0[k], red[t] + red[t + 128]);
}

__global__ __launch_bounds__(256) void k5_norm(float* __restrict__ out,
                                               const float* __restrict__ psum0)
{
    const int t = threadIdx.x;
    const int k = t & 127;
    const int base = blockIdx.x * 2048;
    const float inv = 1.f / fmaxf(psum0[k], EPSF);
#pragma unroll
    for (int i = 0; i < 8; ++i) { int e = base + i * 256 + t; out[e] *= inv; }
}

// ---------------------------------------------------------------- layer1/2 small kernels
__global__ __launch_bounds__(256) void k6_ratio1(
    const float* __restrict__ phi1, const float* __restrict__ theta1,
    const float* __restrict__ theta0, const float* __restrict__ C0,
    float* __restrict__ ratio1)
{
    int g = blockIdx.x * 256 + threadIdx.x;       // 128*512
    int d = g >> 9, b = g & 511;
    float denom = 0.f;
    for (int k = 0; k < 64; ++k) denom = fmaf(phi1[d * 64 + k], theta1[k * NB + b], denom);
    denom = fmaxf(denom, EPSF);
    float xc = theta0[g] * C0[g];
    ratio1[g] = digammaf(denom + xc) - digammaf(denom);
}

__global__ __launch_bounds__(256) void k7_r1(
    const float* __restrict__ ratio1, const float* __restrict__ theta1,
    const float* __restrict__ phi1, float* __restrict__ R1, float* __restrict__ NDot1)
{
    int g = blockIdx.x * 256 + threadIdx.x;       // 128*64
    int d = g >> 6, k = g & 63;
    float s = 0.f;
    for (int b = 0; b < NB; ++b) s = fmaf(ratio1[d * NB + b], theta1[k * NB + b], s);
    R1[g] = s;
    atomicAdd(&NDot1[k], 100.f * phi1[g] * s);
}

__global__ __launch_bounds__(256) void k8_x2(
    const float* __restrict__ phi1, const float* __restrict__ ratio1,
    const float* __restrict__ theta1, float* __restrict__ x2v)
{
    int g = blockIdx.x * 256 + threadIdx.x;       // 64*512
    int kk = g >> 9, b = g & 511;
    float s = 0.f;
    for (int d = 0; d < 128; ++d) s = fmaf(phi1[d * 64 + kk], ratio1[d * NB + b], s);
    x2v[g] = theta1[g] * s;
}

__global__ __launch_bounds__(256) void k10_ratio2(
    const float* __restrict__ phi2, const float* __restrict__ theta2,
    const float* __restrict__ x2v, float* __restrict__ ratio2)
{
    int g = blockIdx.x * 256 + threadIdx.x;       // 64*512
    int d = g >> 9, b = g & 511;
    float denom = 0.f;
    for (int k = 0; k < 32; ++k) denom = fmaf(phi2[d * 32 + k], theta2[k * NB + b], denom);
    denom = fmaxf(denom, EPSF);
    float xc = x2v[g];
    ratio2[g] = digammaf(denom + xc) - digammaf(denom);
}

__global__ __launch_bounds__(256) void k11_r2(
    const float* __restrict__ ratio2, const float* __restrict__ theta2,
    const float* __restrict__ phi2, float* __restrict__ R2, float* __restrict__ NDot2)
{
    int g = blockIdx.x * 256 + threadIdx.x;       // 64*32
    int d = g >> 5, k = g & 31;
    float s = 0.f;
    for (int b = 0; b < NB; ++b) s = fmaf(ratio2[d * NB + b], theta2[k * NB + b], s);
    R2[g] = s;
    atomicAdd(&NDot2[k], 100.f * phi2[g] * s);
}

// one block per column k; blockDim = D (64 or 128)
__global__ void tlasgr_small(const float* __restrict__ phi, const float* __restrict__ R,
                             const float* __restrict__ noise, const float* __restrict__ NDot,
                             float* __restrict__ out, int K, float tmpadd)
{
    const int k = blockIdx.x;
    const int d = threadIdx.x;
    const int D = blockDim.x;
    const int e = d * K + k;
    __shared__ float red[4];
    float nd = NDot[k];
    float inv_n = 1.f / fmaxf(nd, EPSF);
    float tmpsum = nd + tmpadd;
    float phiv = phi[e];
    float tmp = fmaf(100.f * phiv, R[e], 0.1f);
    float step = phiv + inv_n * (tmp - tmpsum * phiv) + sqrtf(2.f * inv_n * phiv) * noise[e];
    float s = step;
#pragma unroll
    for (int o = 1; o < 64; o <<= 1) s += __shfl_xor(s, o);
    if ((d & 63) == 0) red[d >> 6] = s;
    __syncthreads();
    float ssum = (D > 64) ? (red[0] + red[1]) : red[0];
    float p = fmaxf(EPSF, step - (ssum - 1.f) * phiv);
    float q = p;
#pragma unroll
    for (int o = 1; o < 64; o <<= 1) q += __shfl_xor(q, o);
    if ((d & 63) == 0) red[2 + (d >> 6)] = q;
    __syncthreads();
    float psum = (D > 64) ? (red[2] + red[3]) : red[2];
    out[e] = p / fmaxf(psum, EPSF);
}

// ----------------------------------------------------------------
extern "C" void kernel_launch(void* const* d_in, const int* in_sizes, int n_in,
                              void* d_out, int out_size, void* d_ws, size_t ws_size,
                              hipStream_t stream)
{
    const float* x      = (const float*)d_in[0];
    const float* theta0 = (const float*)d_in[1];
    const float* theta1 = (const float*)d_in[2];
    const float* theta2 = (const float*)d_in[3];
    const float* phi0   = (const float*)d_in[4];
    const float* phi1   = (const float*)d_in[5];
    const float* phi2   = (const float*)d_in[6];
    const float* noise0 = (const float*)d_in[7];
    const float* noise1 = (const float*)d_in[8];
    const float* noise2 = (const float*)d_in[9];
    float* out = (float*)d_out;
    float* ws  = (float*)d_ws;

    float* ratio_t  = ws;                  // 15,360,000
    float* C0       = ws + 15360000;       // 65,536
    float* NDot0    = ws + 15425536;       // 128
    float* stepsum0 = ws + 15425664;       // 128
    float* psum0    = ws + 15425792;       // 128
    float* ratio1   = ws + 15425920;       // 65,536
    float* R1       = ws + 15491456;       // 8,192
    float* NDot1    = ws + 15499648;       // 64
    float* x2v      = ws + 15499712;       // 32,768
    float* ratio2   = ws + 15532480;       // 32,768
    float* R2       = ws + 15565248;       // 2,048
    float* NDot2    = ws + 15567296;       // 32 -> total 15,567,328 floats (62.3 MB)

    // zero all atomic accumulators (C0 .. NDot2)
    hipMemsetAsync(C0, 0, (size_t)(15567328 - 15360000) * sizeof(float), stream);

    // layer 0: R0 lives in d_out[0 .. 3,840,000) and is transformed in place
    k1_layer0<<<938, 256, 0, stream>>>(x, phi0, theta0, ratio_t, out, NDot0);
    k2_c0<<<dim3(16, 63), 256, 0, stream>>>(phi0, ratio_t, C0);
    k3_step<<<1875, 256, 0, stream>>>(phi0, noise0, NDot0, out, stepsum0);
    k4_proj<<<1875, 256, 0, stream>>>(phi0, stepsum0, out, psum0);
    k5_norm<<<1875, 256, 0, stream>>>(out, psum0);

    // layer 1
    k6_ratio1<<<256, 256, 0, stream>>>(phi1, theta1, theta0, C0, ratio1);
    k7_r1<<<32, 256, 0, stream>>>(ratio1, theta1, phi1, R1, NDot1);
    k8_x2<<<128, 256, 0, stream>>>(phi1, ratio1, theta1, x2v);
    tlasgr_small<<<64, 128, 0, stream>>>(phi1, R1, noise1, NDot1, out + 3840000, 64, 12.8f);

    // layer 2
    k10_ratio2<<<128, 256, 0, stream>>>(phi2, theta2, x2v, ratio2);
    k11_r2<<<8, 256, 0, stream>>>(ratio2, theta2, phi2, R2, NDot2);
    tlasgr_small<<<32, 64, 0, stream>>>(phi2, R2, noise2, NDot2, out + 3848192, 32, 6.4f);
}

// Round 2
// 327.457 us; speedup vs baseline: 2.5399x; 2.5399x over previous
//
#include <hip/hip_runtime.h>
#include <math.h>

#define EPSF 2.2e-10f
#define NV 30000
#define NB 512

typedef __attribute__((ext_vector_type(8))) short short8;
typedef __attribute__((ext_vector_type(4))) float f32x4;
typedef __attribute__((ext_vector_type(4))) unsigned short ushort4v;

__device__ __forceinline__ unsigned short f2bf(float f) {
    unsigned int u = __float_as_uint(f);
    u += 0x7fffu + ((u >> 16) & 1u);
    return (unsigned short)(u >> 16);
}

// ---------------------------------------------------------------- digamma
__device__ __forceinline__ float digammaf(float xx) {
    float x = xx, r = 0.f;
    while (x < 6.f) { r -= 1.f / x; x += 1.f; }
    float f = 1.f / (x * x);
    float s = logf(x) - 0.5f / x
        - f * (0.0833333333f - f * (0.0083333333f - f * (0.0039682540f
        - f * (0.0041666667f - f * 0.0075757576f))));
    return r + s;
}

// ================================================================ k1 (MFMA)
// Per block: 64 v-rows. Loop over 8 b-chunks of 64:
//   denomT(b,v) = thetaT(b,k) @ phiT(k,v)        [MFMA]
//   ratioT(b,v) = x(b,v) / max(denomT, eps)      -> bf16 to LDS + global
//   R0T(k,v)   += theta(k,b) @ ratioT(b,v)       [MFMA, reg-accum]
// Epilogue: LDS-transpose R0T -> R0(v,k) fp32 writeout + NDot0 atomics.
// LDS XOR swizzle ((row&7)<<4) on every tile (16-way conflict otherwise).
#define TH_BK(b,k)  ((((b) << 8) + ((k) << 1)) ^ (((b) & 7) << 4))
#define TH_KB(k,b)  ((16384 + ((k) << 7) + ((b) << 1)) ^ (((k) & 7) << 4))
#define PHI_VK(v,k) ((32768 + ((v) << 8) + ((k) << 1)) ^ (((v) & 7) << 4))
#define RAT_VB(v,b) ((49152 + ((v) << 7) + ((b) << 1)) ^ (((v) & 7) << 4))
#define RAT_BV(b,v) ((57344 + ((b) << 7) + ((v) << 1)) ^ (((b) & 7) << 4))
#define R0S(v,k)    ((((v) << 9) + ((k) << 2)) ^ (((v) & 7) << 4))

__global__ __launch_bounds__(256, 2) void k1_mfma(
    const float* __restrict__ x,         // (B,V)
    const float* __restrict__ phi0,      // (V,128)
    const float* __restrict__ theta0,    // (128,B)
    unsigned short* __restrict__ ratioT, // (B,V) bf16
    float* __restrict__ R0,              // (V,128) = d_out region
    float* __restrict__ NDot0)           // (128)
{
    __shared__ __align__(16) unsigned char lds[65536];
    const int t = threadIdx.x;
    const int lane = t & 63;
    const int w = t >> 6;
    const int lrow = lane & 15;
    const int lkb = (lane >> 4) << 3;   // k-subblock offset (elements)
    const int lcq = (lane >> 4) << 2;   // C-row quad offset
    const int vbase = blockIdx.x * 64;

    // stage phi_vk (once per block), zero-padded tail
    for (int idx = t; idx < 1024; idx += 256) {
        int v = idx >> 4, kc = (idx & 15) << 3;
        int vg = vbase + v;
        float4 a = {0,0,0,0}, b = {0,0,0,0};
        if (vg < NV) {
            a = *(const float4*)&phi0[vg * 128 + kc];
            b = *(const float4*)&phi0[vg * 128 + kc + 4];
        }
        ushort4v h0 = { f2bf(a.x), f2bf(a.y), f2bf(a.z), f2bf(a.w) };
        ushort4v h1 = { f2bf(b.x), f2bf(b.y), f2bf(b.z), f2bf(b.w) };
        *(ushort4v*)&lds[PHI_VK(v, kc)]     = h0;
        *(ushort4v*)&lds[PHI_VK(v, kc + 4)] = h1;
    }

    f32x4 racc[2][4];
#pragma unroll
    for (int tr = 0; tr < 2; ++tr)
#pragma unroll
        for (int j = 0; j < 4; ++j) racc[tr][j] = (f32x4){0.f, 0.f, 0.f, 0.f};

    for (int c = 0; c < 8; ++c) {
        const int b0c = c * 64;
        __syncthreads();   // prev chunk's reads of th/rat done
        // stage theta chunk: th_kb (coalesced) + th_bk (8-way scatter, swizzle-spread)
        for (int idx = t; idx < 1024; idx += 256) {
            int k = idx >> 3, bg = (idx & 7) << 3;
            float4 a = *(const float4*)&theta0[k * NB + b0c + bg];
            float4 b = *(const float4*)&theta0[k * NB + b0c + bg + 4];
            unsigned short h[8] = { f2bf(a.x), f2bf(a.y), f2bf(a.z), f2bf(a.w),
                                    f2bf(b.x), f2bf(b.y), f2bf(b.z), f2bf(b.w) };
            ushort4v p0 = { h[0], h[1], h[2], h[3] };
            ushort4v p1 = { h[4], h[5], h[6], h[7] };
            *(ushort4v*)&lds[TH_KB(k, bg)]     = p0;
            *(ushort4v*)&lds[TH_KB(k, bg + 4)] = p1;
#pragma unroll
            for (int i = 0; i < 8; ++i)
                *(unsigned short*)&lds[TH_BK(bg + i, k)] = h[i];
        }
        __syncthreads();

        // denomT: wave w owns b-rows [w*16, w*16+16), all 64 v
        f32x4 dacc[4];
#pragma unroll
        for (int j = 0; j < 4; ++j) dacc[j] = (f32x4){0.f, 0.f, 0.f, 0.f};
#pragma unroll
        for (int ks = 0; ks < 4; ++ks) {
            short8 afr = *(const short8*)&lds[TH_BK(w * 16 + lrow, ks * 32 + lkb)];
#pragma unroll
            for (int j = 0; j < 4; ++j) {
                short8 bfr = *(const short8*)&lds[PHI_VK(j * 16 + lrow, ks * 32 + lkb)];
                dacc[j] = __builtin_amdgcn_mfma_f32_16x16x32_bf16(afr, bfr, dacc[j], 0, 0, 0);
            }
        }
        // ratio = x / max(denom,eps); pack bf16 into rat_vb + rat_bv
#pragma unroll
        for (int j = 0; j < 4; ++j) {
            const int vloc = j * 16 + lrow;
            const int vg = vbase + vloc;
            const int bloc = w * 16 + lcq;
            ushort4v h;
#pragma unroll
            for (int i = 0; i < 4; ++i) {
                float den = fmaxf(dacc[j][i], EPSF);
                float xv = (vg < NV) ? x[(b0c + bloc + i) * NV + vg] : 0.f;
                float r = xv / den;
                h[i] = f2bf(r);
                *(unsigned short*)&lds[RAT_BV(bloc + i, vloc)] = h[i];
            }
            *(ushort4v*)&lds[RAT_VB(vloc, bloc)] = h;
        }
        __syncthreads();

        // R0T += theta(k,b) @ ratioT(b,v): wave w owns k-rows [w*32, w*32+32)
#pragma unroll
        for (int ks = 0; ks < 2; ++ks) {
            short8 bfr[4];
#pragma unroll
            for (int j = 0; j < 4; ++j)
                bfr[j] = *(const short8*)&lds[RAT_VB(j * 16 + lrow, ks * 32 + lkb)];
#pragma unroll
            for (int tr = 0; tr < 2; ++tr) {
                short8 afr = *(const short8*)&lds[TH_KB(w * 32 + tr * 16 + lrow, ks * 32 + lkb)];
#pragma unroll
                for (int j = 0; j < 4; ++j)
                    racc[tr][j] = __builtin_amdgcn_mfma_f32_16x16x32_bf16(afr, bfr[j], racc[tr][j], 0, 0, 0);
            }
        }
        // ratioT global writeout (coalesced from rat_bv)
        for (int idx = t; idx < 512; idx += 256) {
            int b = idx >> 3, vgr = (idx & 7) << 3;
            short8 val = *(const short8*)&lds[RAT_BV(b, vgr)];
            int vg = vbase + vgr;
            if (vg + 7 < NV) {
                *(short8*)&ratioT[(size_t)(b0c + b) * NV + vg] = val;
            } else {
#pragma unroll
                for (int e = 0; e < 8; ++e)
                    if (vg + e < NV) ratioT[(size_t)(b0c + b) * NV + vg + e] = ((unsigned short*)&val)[e];
            }
        }
    }

    // epilogue: transpose R0T -> R0(v,k) via LDS, writeout + NDot0
    __syncthreads();
#pragma unroll
    for (int tr = 0; tr < 2; ++tr)
#pragma unroll
        for (int j = 0; j < 4; ++j) {
            int vloc = j * 16 + lrow;
            int k0 = w * 32 + tr * 16 + lcq;
            *(f32x4*)&lds[R0S(vloc, k0)] = racc[tr][j];
        }
    __syncthreads();
    float nd = 0.f;
    const int kf = t & 127;
    for (int idx = t; idx < 8192; idx += 256) {
        int v = idx >> 7;
        int vg = vbase + v;
        float val = *(const float*)&lds[R0S(v, kf)];
        if (vg < NV) {
            R0[vg * 128 + kf] = val;
            nd += val * phi0[vg * 128 + kf];
        }
    }
    float* red = (float*)&lds[49152];
    red[t] = nd;
    __syncthreads();
    if (t < 128) atomicAdd(&NDot0[kf], 100.f * (red[t] + red[t + 128]));
}

// ================================================================ k2 (MFMA)
// C0(k,b) = phiT(k,v) @ ratio(v,b), split-V with atomic reduce.
#define PHI_KV(k,v)  ((((k) << 7) + ((v) << 1)) ^ (((k) & 7) << 4))
#define RAT_BV2(b,v) ((16384 + ((b) << 7) + ((v) << 1)) ^ (((b) & 7) << 4))

__global__ __launch_bounds__(256, 2) void k2_mfma(
    const float* __restrict__ phi0,            // (V,128)
    const unsigned short* __restrict__ ratioT, // (B,V) bf16
    float* __restrict__ C0)                    // (128,512) pre-zeroed
{
    __shared__ __align__(16) unsigned char lds[32768];
    const int t = threadIdx.x;
    const int lane = t & 63;
    const int w = t >> 6;
    const int lrow = lane & 15;
    const int lkb = (lane >> 4) << 3;
    const int lcq = (lane >> 4) << 2;
    const int btile = blockIdx.x & 3;
    const int split = blockIdx.x >> 2;   // 64 splits
    const int b0 = btile * 128;

    f32x4 acc[2][8];
#pragma unroll
    for (int tr = 0; tr < 2; ++tr)
#pragma unroll
        for (int bt = 0; bt < 8; ++bt) acc[tr][bt] = (f32x4){0.f, 0.f, 0.f, 0.f};

    for (int ci = split; ci < 469; ci += 64) {
        const int v0 = ci * 64;
        __syncthreads();
        // stage phi transposed -> phi_kv (8-way scatter, swizzle-spread)
        for (int idx = t; idx < 1024; idx += 256) {
            int v = idx >> 4, kg = (idx & 15) << 3;
            int vg = v0 + v;
            float4 a = {0,0,0,0}, b = {0,0,0,0};
            if (vg < NV) {
                a = *(const float4*)&phi0[vg * 128 + kg];
                b = *(const float4*)&phi0[vg * 128 + kg + 4];
            }
            unsigned short h[8] = { f2bf(a.x), f2bf(a.y), f2bf(a.z), f2bf(a.w),
                                    f2bf(b.x), f2bf(b.y), f2bf(b.z), f2bf(b.w) };
#pragma unroll
            for (int i = 0; i < 8; ++i)
                *(unsigned short*)&lds[PHI_KV(kg + i, v)] = h[i];
        }
        // stage ratio tile (coalesced bf16)
        for (int idx = t; idx < 1024; idx += 256) {
            int b = idx >> 3, vg8 = (idx & 7) << 3;
            int vg = v0 + vg8;
            short8 val;
            if (vg + 7 < NV) {
                val = *(const short8*)&ratioT[(size_t)(b0 + b) * NV + vg];
            } else {
#pragma unroll
                for (int e = 0; e < 8; ++e)
                    ((unsigned short*)&val)[e] = (vg + e < NV) ? ratioT[(size_t)(b0 + b) * NV + vg + e] : 0;
            }
            *(short8*)&lds[RAT_BV2(b, vg8)] = val;
        }
        __syncthreads();
        // wave w: k-rows [w*32, w*32+32) x 128 b
#pragma unroll
        for (int ks = 0; ks < 2; ++ks) {
            short8 a0 = *(const short8*)&lds[PHI_KV(w * 32 + lrow,      ks * 32 + lkb)];
            short8 a1 = *(const short8*)&lds[PHI_KV(w * 32 + 16 + lrow, ks * 32 + lkb)];
#pragma unroll
            for (int bt = 0; bt < 8; ++bt) {
                short8 bb = *(const short8*)&lds[RAT_BV2(bt * 16 + lrow, ks * 32 + lkb)];
                acc[0][bt] = __builtin_amdgcn_mfma_f32_16x16x32_bf16(a0, bb, acc[0][bt], 0, 0, 0);
                acc[1][bt] = __builtin_amdgcn_mfma_f32_16x16x32_bf16(a1, bb, acc[1][bt], 0, 0, 0);
            }
        }
    }
#pragma unroll
    for (int tr = 0; tr < 2; ++tr)
#pragma unroll
        for (int bt = 0; bt < 8; ++bt)
#pragma unroll
            for (int i = 0; i < 4; ++i) {
                int k = w * 32 + tr * 16 + lcq + i;
                int b = b0 + bt * 16 + lrow;
                atomicAdd(&C0[k * NB + b], acc[tr][bt][i]);
            }
}

// ---------------------------------------------------------------- layer0 finalize
__global__ __launch_bounds__(256) void k3_step(
    const float* __restrict__ phi0, const float* __restrict__ noise0,
    const float* __restrict__ NDot0, float* __restrict__ out,
    float* __restrict__ stepsum0)
{
    __shared__ float red[256];
    const int t = threadIdx.x;
    const int k = t & 127;
    const int base = blockIdx.x * 2048;
    float nd = NDot0[k];
    float inv_n = 1.f / fmaxf(nd, EPSF);
    float tmpsum = nd + 3000.f;
    float ssum = 0.f;
#pragma unroll
    for (int i = 0; i < 8; ++i) {
        int e = base + i * 256 + t;
        float phi = phi0[e], R = out[e], nz = noise0[e];
        float tmp = fmaf(100.f * phi, R, 0.1f);
        float step = phi + inv_n * (tmp - tmpsum * phi) + sqrtf(2.f * inv_n * phi) * nz;
        out[e] = step;
        ssum += step;
    }
    red[t] = ssum;
    __syncthreads();
    if (t < 128) atomicAdd(&stepsum0[k], red[t] + red[t + 128]);
}

__global__ __launch_bounds__(256) void k4_proj(
    const float* __restrict__ phi0, const float* __restrict__ stepsum0,
    float* __restrict__ out, float* __restrict__ psum0)
{
    __shared__ float red[256];
    const int t = threadIdx.x;
    const int k = t & 127;
    const int base = blockIdx.x * 2048;
    const float ss = stepsum0[k] - 1.f;
    float ps = 0.f;
#pragma unroll
    for (int i = 0; i < 8; ++i) {
        int e = base + i * 256 + t;
        float p = out[e] - ss * phi0[e];
        p = fmaxf(EPSF, p);
        out[e] = p;
        ps += p;
    }
    red[t] = ps;
    __syncthreads();
    if (t < 128) atomicAdd(&psum0[k], red[t] + red[t + 128]);
}

__global__ __launch_bounds__(256) void k5_norm(float* __restrict__ out,
                                               const float* __restrict__ psum0)
{
    const int t = threadIdx.x;
    const int k = t & 127;
    const int base = blockIdx.x * 2048;
    const float inv = 1.f / fmaxf(psum0[k], EPSF);
#pragma unroll
    for (int i = 0; i < 8; ++i) { int e = base + i * 256 + t; out[e] *= inv; }
}

// ---------------------------------------------------------------- layer1/2 small kernels
__global__ __launch_bounds__(256) void k6_ratio1(
    const float* __restrict__ phi1, const float* __restrict__ theta1,
    const float* __restrict__ theta0, const float* __restrict__ C0,
    float* __restrict__ ratio1)
{
    int g = blockIdx.x * 256 + threadIdx.x;       // 128*512
    int d = g >> 9, b = g & 511;
    float denom = 0.f;
    for (int k = 0; k < 64; ++k) denom = fmaf(phi1[d * 64 + k], theta1[k * NB + b], denom);
    denom = fmaxf(denom, EPSF);
    float xc = theta0[g] * C0[g];
    ratio1[g] = digammaf(denom + xc) - digammaf(denom);
}

__global__ __launch_bounds__(256) void k7_r1_w(
    const float* __restrict__ ratio1, const float* __restrict__ theta1,
    const float* __restrict__ phi1, float* __restrict__ R1, float* __restrict__ NDot1)
{
    int wid = (blockIdx.x * 256 + threadIdx.x) >> 6;  // 8192 waves: (d,k)
    int lane = threadIdx.x & 63;
    int d = wid >> 6, kk = wid & 63;
    float s = 0.f;
#pragma unroll
    for (int i = 0; i < 8; ++i) {
        int b = i * 64 + lane;
        s = fmaf(ratio1[d * NB + b], theta1[kk * NB + b], s);
    }
#pragma unroll
    for (int o = 1; o < 64; o <<= 1) s += __shfl_xor(s, o);
    if (lane == 0) {
        R1[wid] = s;
        atomicAdd(&NDot1[kk], 100.f * phi1[wid] * s);
    }
}

__global__ __launch_bounds__(256) void k8_x2(
    const float* __restrict__ phi1, const float* __restrict__ ratio1,
    const float* __restrict__ theta1, float* __restrict__ x2v)
{
    int g = blockIdx.x * 256 + threadIdx.x;       // 64*512
    int kk = g >> 9, b = g & 511;
    float s = 0.f;
    for (int d = 0; d < 128; ++d) s = fmaf(phi1[d * 64 + kk], ratio1[d * NB + b], s);
    x2v[g] = theta1[g] * s;
}

__global__ __launch_bounds__(256) void k10_ratio2(
    const float* __restrict__ phi2, const float* __restrict__ theta2,
    const float* __restrict__ x2v, float* __restrict__ ratio2)
{
    int g = blockIdx.x * 256 + threadIdx.x;       // 64*512
    int d = g >> 9, b = g & 511;
    float denom = 0.f;
    for (int k = 0; k < 32; ++k) denom = fmaf(phi2[d * 32 + k], theta2[k * NB + b], denom);
    denom = fmaxf(denom, EPSF);
    float xc = x2v[g];
    ratio2[g] = digammaf(denom + xc) - digammaf(denom);
}

__global__ __launch_bounds__(256) void k11_r2_w(
    const float* __restrict__ ratio2, const float* __restrict__ theta2,
    const float* __restrict__ phi2, float* __restrict__ R2, float* __restrict__ NDot2)
{
    int wid = (blockIdx.x * 256 + threadIdx.x) >> 6;  // 2048 waves: (d,k)
    int lane = threadIdx.x & 63;
    int d = wid >> 5, kk = wid & 31;
    float s = 0.f;
#pragma unroll
    for (int i = 0; i < 8; ++i) {
        int b = i * 64 + lane;
        s = fmaf(ratio2[d * NB + b], theta2[kk * NB + b], s);
    }
#pragma unroll
    for (int o = 1; o < 64; o <<= 1) s += __shfl_xor(s, o);
    if (lane == 0) {
        R2[wid] = s;
        atomicAdd(&NDot2[kk], 100.f * phi2[wid] * s);
    }
}

// one block per column k; blockDim = D (64 or 128)
__global__ void tlasgr_small(const float* __restrict__ phi, const float* __restrict__ R,
                             const float* __restrict__ noise, const float* __restrict__ NDot,
                             float* __restrict__ out, int K, float tmpadd)
{
    const int k = blockIdx.x;
    const int d = threadIdx.x;
    const int D = blockDim.x;
    const int e = d * K + k;
    __shared__ float red[4];
    float nd = NDot[k];
    float inv_n = 1.f / fmaxf(nd, EPSF);
    float tmpsum = nd + tmpadd;
    float phiv = phi[e];
    float tmp = fmaf(100.f * phiv, R[e], 0.1f);
    float step = phiv + inv_n * (tmp - tmpsum * phiv) + sqrtf(2.f * inv_n * phiv) * noise[e];
    float s = step;
#pragma unroll
    for (int o = 1; o < 64; o <<= 1) s += __shfl_xor(s, o);
    if ((d & 63) == 0) red[d >> 6] = s;
    __syncthreads();
    float ssum = (D > 64) ? (red[0] + red[1]) : red[0];
    float p = fmaxf(EPSF, step - (ssum - 1.f) * phiv);
    float q = p;
#pragma unroll
    for (int o = 1; o < 64; o <<= 1) q += __shfl_xor(q, o);
    if ((d & 63) == 0) red[2 + (d >> 6)] = q;
    __syncthreads();
    float psum = (D > 64) ? (red[2] + red[3]) : red[2];
    out[e] = p / fmaxf(psum, EPSF);
}

// ----------------------------------------------------------------
extern "C" void kernel_launch(void* const* d_in, const int* in_sizes, int n_in,
                              void* d_out, int out_size, void* d_ws, size_t ws_size,
                              hipStream_t stream)
{
    const float* x      = (const float*)d_in[0];
    const float* theta0 = (const float*)d_in[1];
    const float* theta1 = (const float*)d_in[2];
    const float* theta2 = (const float*)d_in[3];
    const float* phi0   = (const float*)d_in[4];
    const float* phi1   = (const float*)d_in[5];
    const float* phi2   = (const float*)d_in[6];
    const float* noise0 = (const float*)d_in[7];
    const float* noise1 = (const float*)d_in[8];
    const float* noise2 = (const float*)d_in[9];
    float* out = (float*)d_out;
    float* ws  = (float*)d_ws;

    unsigned short* ratioT = (unsigned short*)ws;  // (512,30000) bf16 = 7,680,000 float slots
    float* C0       = ws + 7680000;       // 65,536  (atomic)
    float* NDot0    = ws + 7745536;       // 128     (atomic)
    float* stepsum0 = ws + 7745664;       // 128     (atomic)
    float* psum0    = ws + 7745792;       // 128     (atomic)
    float* NDot1    = ws + 7745920;       // 64      (atomic)
    float* NDot2    = ws + 7745984;       // 32      (atomic)
    float* ratio1   = ws + 7746048;       // 65,536
    float* R1       = ws + 7811584;       // 8,192
    float* x2v      = ws + 7819776;       // 32,768
    float* ratio2   = ws + 7852544;       // 32,768
    float* R2       = ws + 7885312;       // 2,048

    // zero all atomic accumulators (C0 .. NDot2: 66,016 floats)
    hipMemsetAsync(C0, 0, 66016 * sizeof(float), stream);

    // layer 0: R0 lives in d_out[0 .. 3,840,000) and is transformed in place
    k1_mfma<<<469, 256, 0, stream>>>(x, phi0, theta0, ratioT, out, NDot0);
    k2_mfma<<<256, 256, 0, stream>>>(phi0, ratioT, C0);
    k3_step<<<1875, 256, 0, stream>>>(phi0, noise0, NDot0, out, stepsum0);
    k4_proj<<<1875, 256, 0, stream>>>(phi0, stepsum0, out, psum0);
    k5_norm<<<1875, 256, 0, stream>>>(out, psum0);

    // layer 1
    k6_ratio1<<<256, 256, 0, stream>>>(phi1, theta1, theta0, C0, ratio1);
    k7_r1_w<<<2048, 256, 0, stream>>>(ratio1, theta1, phi1, R1, NDot1);
    k8_x2<<<128, 256, 0, stream>>>(phi1, ratio1, theta1, x2v);
    tlasgr_small<<<64, 128, 0, stream>>>(phi1, R1, noise1, NDot1, out + 3840000, 64, 12.8f);

    // layer 2
    k10_ratio2<<<128, 256, 0, stream>>>(phi2, theta2, x2v, ratio2);
    k11_r2_w<<<512, 256, 0, stream>>>(ratio2, theta2, phi2, R2, NDot2);
    tlasgr_small<<<32, 64, 0, stream>>>(phi2, R2, noise2, NDot2, out + 3848192, 32, 6.4f);
}